// Round 19
// baseline (29.452 us; speedup 1.0000x reference)
//
#include <hip/hip_runtime.h>
#include <hip/hip_bf16.h>

typedef __attribute__((ext_vector_type(8))) short short8;
typedef __attribute__((ext_vector_type(4))) float f32x4;

#define NQ 32      // queries
#define NM 32      // query tokens
#define NH 128     // head dim
#define ND 512     // docs
#define NN 180     // doc tokens
#define NTMAX 12   // max compacted n-tiles (192 rows)

#define QFRAG_BYTES (NQ * 2 * 4 * 64 * 16)     // 256 KB
#define MAPINV_OFF  QFRAG_BYTES                // ushort[512][192] = 192 KB
#define CNT_OFF     (MAPINV_OFF + ND * 192 * 2)

static __device__ __forceinline__ unsigned short f2bf(float x) {
  __hip_bfloat16 h = __float2bfloat16(x);
  return __builtin_bit_cast(unsigned short, h);
}

static __device__ __forceinline__ uint4 pack8m(const float* v, float m) {
  unsigned int a = (unsigned)f2bf(v[0] * m) | ((unsigned)f2bf(v[1] * m) << 16);
  unsigned int b = (unsigned)f2bf(v[2] * m) | ((unsigned)f2bf(v[3] * m) << 16);
  unsigned int c = (unsigned)f2bf(v[4] * m) | ((unsigned)f2bf(v[5] * m) << 16);
  unsigned int e = (unsigned)f2bf(v[6] * m) | ((unsigned)f2bf(v[7] * m) << 16);
  return make_uint4(a, b, c, e);
}

static __device__ __forceinline__ uint4 pack8(float4 a, float4 b) {
  unsigned int x = (unsigned)f2bf(a.x) | ((unsigned)f2bf(a.y) << 16);
  unsigned int y = (unsigned)f2bf(a.z) | ((unsigned)f2bf(a.w) << 16);
  unsigned int z = (unsigned)f2bf(b.x) | ((unsigned)f2bf(b.y) << 16);
  unsigned int u = (unsigned)f2bf(b.z) | ((unsigned)f2bf(b.w) << 16);
  return make_uint4(x, y, z, u);
}

// Fragment layout (16x16x32 bf16, swapped operands): element (lane,j) of tile
// (t, ks) = M[t*16 + (lane&15)][ks*32 + (lane>>4)*8 + j], stored 16B/lane.
//
// prep (tiny): blocks 0..63 = Q fragments (masked bf16); blocks 64..575 =
// per-doc mask scan -> mapinv_g[d][0..191] (compacted src rows, ZERO-padded
// for dr>=cnt) + cnt[d]. No Dc data write (fused gathers D directly).
__global__ __launch_bounds__(256) void prep_kernel(
    const float* __restrict__ Q, const int* __restrict__ qmask,
    const int* __restrict__ dmask, unsigned short* __restrict__ Qb,
    unsigned short* __restrict__ mapinv_g, int* __restrict__ cnt_arr) {
  const int tid = threadIdx.x;

  if (blockIdx.x < 64) {
    int idx = blockIdx.x * 256 + tid;   // 16384 fragment-lanes
    int lane = idx & 63;
    int ks = (idx >> 6) & 3;
    int mt = (idx >> 8) & 1;
    int q  = idx >> 9;
    int row = mt * 16 + (lane & 15);
    int k0  = ks * 32 + (lane >> 4) * 8;
    const float* src = Q + (q * NM + row) * NH + k0;
    float v[8];
    *reinterpret_cast<float4*>(&v[0]) = *reinterpret_cast<const float4*>(src);
    *reinterpret_cast<float4*>(&v[4]) = *reinterpret_cast<const float4*>(src + 4);
    float m = (float)qmask[q * NM + row];
    reinterpret_cast<uint4*>(Qb)[idx] = pack8m(v, m);
  } else {
    __shared__ int wtot[3];
    const int d = blockIdx.x - 64;
    const int lane = tid & 63;
    const int w = tid >> 6;

    int flag = 0, pre = 0;
    if (tid < NN) flag = dmask[d * NN + tid];
    if (tid < 192) {   // waves 0..2
      unsigned long long bal = __ballot(flag != 0);
      pre = __popcll(bal & ((1ull << lane) - 1ull));
      if (lane == 63) wtot[w] = pre + (flag ? 1 : 0);
    }
    __syncthreads();
    const int cnt = wtot[0] + wtot[1] + wtot[2];
    // pads (index >= cnt) get 0; valid scatter targets are < cnt -> disjoint
    if (tid < 192 && tid >= cnt) mapinv_g[d * 192 + tid] = 0;
    if (tid < 192 && flag) {
      int base = (w >= 1 ? wtot[0] : 0) + (w >= 2 ? wtot[1] : 0);
      mapinv_g[d * 192 + pre + base] = (unsigned short)tid;
    }
    if (tid == 0) cnt_arr[d] = cnt;
  }
}

// FUSED maxsim: 1024 blocks x 256 thr (4 waves); block = (doc, query-half),
// XCD-paired (d = ((bid>>4)<<3)|(bid&7)) so both halves share one XCD's L2 ->
// D gathered from HBM ~once. LDS 48KB -> 3 blocks/CU resident + queue: blocks
// DESTAGGER so one block's stage hides under the others' compute (R14's 2/CU
// lockstep never overlapped phases). Stage is BRANCHLESS straight-line:
// 12 precomputed-row gathers (pads = row 0, excluded later by tail mask),
// all 24 global loads in one latency window. Compute = R14's proven body;
// wave w owns queries qh*16 + w*4 .. +3 as two sequential pairs.
// ~125 VGPR, cap 128 via __launch_bounds__(256,4).
__global__ __launch_bounds__(256, 4) void fused_maxsim(
    const float* __restrict__ D, const unsigned short* __restrict__ mapinv_g,
    const int* __restrict__ cnt_arr, const unsigned short* __restrict__ Qb,
    float* __restrict__ out) {
  __shared__ __attribute__((aligned(16))) unsigned char Dlds[NTMAX * 4096];
  const int bid = blockIdx.x;
  const int d  = ((bid >> 4) << 3) | (bid & 7);
  const int qh = (bid >> 3) & 1;
  const int tid = threadIdx.x;
  const int lane = tid & 63;
  const int w = tid >> 6;
  const int bg = lane >> 4;
  const float NEG = -__builtin_inff();

  const int cnt = cnt_arr[d];
  const int ntc = (cnt + 15) >> 4;

  // ---- branchless stage: tile u slot = byte (u*256 + tid)*16 ----
  {
    const unsigned short* mig = mapinv_g + d * 192;
    const int sbl = tid & 15;            // row-in-tile
    const int sks = tid >> 6;            // frag ks (0..3)
    const int sbg = (tid >> 4) & 3;      // k-subgroup
    unsigned short srow[NTMAX];
    #pragma unroll
    for (int u = 0; u < NTMAX; ++u) srow[u] = mig[u * 16 + sbl];
    #pragma unroll
    for (int u = 0; u < NTMAX; ++u) {
      const float4* p = reinterpret_cast<const float4*>(D) +
                        (size_t)(d * NN + srow[u]) * 32 + sks * 8 + sbg * 2;
      uint4 o = pack8(p[0], p[1]);
      *reinterpret_cast<uint4*>(&Dlds[(size_t)(u * 256 + tid) * 16]) = o;
    }
  }
  __syncthreads();

  // ---- compute: two sequential pairs per wave (R14 body) ----
  #pragma unroll 1
  for (int p = 0; p < 2; ++p) {
    const int q0 = qh * 16 + w * 4 + p * 2;

    short8 Qf[2][2][4];  // [qi][mt][ks], 64 VGPR, plain loads (stay resident)
    #pragma unroll
    for (int qi = 0; qi < 2; ++qi)
      #pragma unroll
      for (int mt = 0; mt < 2; ++mt)
        #pragma unroll
        for (int ks = 0; ks < 4; ++ks)
          Qf[qi][mt][ks] = *reinterpret_cast<const short8*>(
              reinterpret_cast<const char*>(Qb) +
              ((((q0 + qi) * 2 + mt) * 4 + ks) << 10) + (lane << 4));

    float run[2][2];
    #pragma unroll
    for (int qi = 0; qi < 2; ++qi)
      #pragma unroll
      for (int mt = 0; mt < 2; ++mt) run[qi][mt] = NEG;

    #pragma unroll 2
    for (int nt = 0; nt < ntc; ++nt) {
      short8 Da[4];
      #pragma unroll
      for (int ks = 0; ks < 4; ++ks)
        Da[ks] = *reinterpret_cast<const short8*>(
            &Dlds[((nt * 4 + ks) << 10) + (lane << 4)]);

      f32x4 acc[2][2];
      #pragma unroll
      for (int qi = 0; qi < 2; ++qi)
        #pragma unroll
        for (int mt = 0; mt < 2; ++mt) acc[qi][mt] = (f32x4){0.f, 0.f, 0.f, 0.f};

      #pragma unroll
      for (int ks = 0; ks < 4; ++ks)
        #pragma unroll
        for (int qi = 0; qi < 2; ++qi)
          #pragma unroll
          for (int mt = 0; mt < 2; ++mt)
            acc[qi][mt] = __builtin_amdgcn_mfma_f32_16x16x32_bf16(
                Da[ks], Qf[qi][mt][ks], acc[qi][mt], 0, 0, 0);

      if (nt * 16 + 16 > cnt) {
        // tail tile: lane holds rows nt*16 + bg*4 + j; valid iff j < rlim
        const int rlim = cnt - nt * 16 - bg * 4;
        #pragma unroll
        for (int qi = 0; qi < 2; ++qi)
          #pragma unroll
          for (int mt = 0; mt < 2; ++mt) {
            float vmax = NEG;
            #pragma unroll
            for (int j = 0; j < 4; ++j) {
              float v = (j < rlim) ? acc[qi][mt][j] : NEG;
              vmax = fmaxf(vmax, v);
            }
            run[qi][mt] = fmaxf(run[qi][mt], vmax);
          }
      } else {
        #pragma unroll
        for (int qi = 0; qi < 2; ++qi)
          #pragma unroll
          for (int mt = 0; mt < 2; ++mt) {
            float vmax = fmaxf(fmaxf(acc[qi][mt][0], acc[qi][mt][1]),
                               fmaxf(acc[qi][mt][2], acc[qi][mt][3]));
            run[qi][mt] = fmaxf(run[qi][mt], vmax);
          }
      }
    }

    // masked doc tokens inject an exact 0 into max_n
    if (cnt < NN) {
      #pragma unroll
      for (int qi = 0; qi < 2; ++qi)
        #pragma unroll
        for (int mt = 0; mt < 2; ++mt) run[qi][mt] = fmaxf(run[qi][mt], 0.f);
    }

    // reduction: xor16/32 max over n-quarters, xor1..8 sum over m
    #pragma unroll
    for (int qi = 0; qi < 2; ++qi) {
      float a = run[qi][0];   // m = lane&15
      float bb = run[qi][1];  // m = (lane&15)+16
      a = fmaxf(a, __shfl_xor(a, 16));
      a = fmaxf(a, __shfl_xor(a, 32));
      bb = fmaxf(bb, __shfl_xor(bb, 16));
      bb = fmaxf(bb, __shfl_xor(bb, 32));
      float s = a + bb;
      s += __shfl_xor(s, 1);
      s += __shfl_xor(s, 2);
      s += __shfl_xor(s, 4);
      s += __shfl_xor(s, 8);
      if (lane == 0) out[(q0 + qi) * ND + d] = s;
    }
  }
}

extern "C" void kernel_launch(void* const* d_in, const int* in_sizes, int n_in,
                              void* d_out, int out_size, void* d_ws, size_t ws_size,
                              hipStream_t stream) {
  const float* Q = (const float*)d_in[0];
  const float* D = (const float*)d_in[1];
  const int* qmask = (const int*)d_in[2];
  const int* dmask = (const int*)d_in[3];
  float* out = (float*)d_out;

  unsigned short* Qb = (unsigned short*)d_ws;
  unsigned short* mapinv_g = (unsigned short*)((char*)d_ws + MAPINV_OFF);
  int* cnt_arr = (int*)((char*)d_ws + CNT_OFF);

  prep_kernel<<<64 + ND, 256, 0, stream>>>(Q, qmask, dmask, Qb, mapinv_g, cnt_arr);
  fused_maxsim<<<ND * 2, 256, 0, stream>>>(D, mapinv_g, cnt_arr, Qb, out);
}

// Round 21
// 26.021 us; speedup vs baseline: 1.1319x; 1.1319x over previous
//
#include <hip/hip_runtime.h>
#include <hip/hip_bf16.h>

typedef __attribute__((ext_vector_type(8))) short short8;
typedef __attribute__((ext_vector_type(4))) float f32x4;

#define NQ 32      // queries
#define NM 32      // query tokens
#define NH 128     // head dim
#define ND 512     // docs
#define NN 180     // doc tokens
#define NTMAX 12   // max compacted n-tiles (192 rows)

#define QFRAG_BYTES (NQ * 2 * 4 * 64 * 16)   // 256 KB frag-ordered Q in d_ws

static __device__ __forceinline__ unsigned short f2bf(float x) {
  __hip_bfloat16 h = __float2bfloat16(x);
  return __builtin_bit_cast(unsigned short, h);
}

static __device__ __forceinline__ uint4 pack8m(const float* v, float m) {
  unsigned int a = (unsigned)f2bf(v[0] * m) | ((unsigned)f2bf(v[1] * m) << 16);
  unsigned int b = (unsigned)f2bf(v[2] * m) | ((unsigned)f2bf(v[3] * m) << 16);
  unsigned int c = (unsigned)f2bf(v[4] * m) | ((unsigned)f2bf(v[5] * m) << 16);
  unsigned int e = (unsigned)f2bf(v[6] * m) | ((unsigned)f2bf(v[7] * m) << 16);
  return make_uint4(a, b, c, e);
}

static __device__ __forceinline__ uint4 pack8(float4 a, float4 b) {
  unsigned int x = (unsigned)f2bf(a.x) | ((unsigned)f2bf(a.y) << 16);
  unsigned int y = (unsigned)f2bf(a.z) | ((unsigned)f2bf(a.w) << 16);
  unsigned int z = (unsigned)f2bf(b.x) | ((unsigned)f2bf(b.y) << 16);
  unsigned int u = (unsigned)f2bf(b.z) | ((unsigned)f2bf(b.w) << 16);
  return make_uint4(x, y, z, u);
}

// Fragment layout (16x16x32 bf16, swapped operands): element (lane,j) of tile
// (t, ks) = M[t*16 + (lane&15)][ks*32 + (lane>>4)*8 + j], stored 16B/lane.

// Qb_frag[q][mt][ks][lane][8]: MFMA-ready masked bf16 Q fragments (tiny kernel).
__global__ __launch_bounds__(256) void prep_q_frag(
    const float* __restrict__ Q, const int* __restrict__ qmask,
    unsigned short* __restrict__ Qb) {
  int idx = blockIdx.x * 256 + threadIdx.x;   // 16384 fragment-lanes
  int lane = idx & 63;
  int ks = (idx >> 6) & 3;
  int mt = (idx >> 8) & 1;
  int q  = idx >> 9;
  int row = mt * 16 + (lane & 15);
  int k0  = ks * 32 + (lane >> 4) * 8;
  const float* src = Q + (q * NM + row) * NH + k0;
  float v[8];
  *reinterpret_cast<float4*>(&v[0]) = *reinterpret_cast<const float4*>(src);
  *reinterpret_cast<float4*>(&v[4]) = *reinterpret_cast<const float4*>(src + 4);
  float m = (float)qmask[q * NM + row];
  reinterpret_cast<uint4*>(Qb)[idx] = pack8m(v, m);
}

// FUSED per-doc kernel (R14, best-verified 25.9 us): 512 blocks x 512 thr.
//  1) compaction map (ballot prefix-scan over the 180 mask flags)
//  2) stage compacted VALID rows -> LDS as bf16 MFMA-frag tiles (pad rows = 0;
//     no mask multiply needed for valid rows); D read once (~23.5 MB HBM)
//  3) each wave computes 2 query pairs SEQUENTIALLY (#pragma unroll 1 -> one
//     pair's ~104 VGPR live; cap 128 via __launch_bounds__(512,4) = 4 waves/
//     SIMD with both co-resident blocks; VGPR pool is 512/SIMD)
// Masked doc tokens inject exactly 0 into max_n -> clamp once iff cnt<NN.
// [R20 lesson: no cooperative launch under graph capture; R15-R19 lessons:
//  batched stage, split prep, doc-halving, computed-Qf all regress vs this.]
__global__ __launch_bounds__(512, 4) void fused_maxsim(
    const float* __restrict__ D, const int* __restrict__ dmask,
    const unsigned short* __restrict__ Qb, float* __restrict__ out) {
  __shared__ unsigned char Dlds[NTMAX * 4096];   // 49152 B frag-order tiles
  __shared__ unsigned short mapinv[192];
  __shared__ int wtot[4];
  const int d = blockIdx.x;
  const int tid = threadIdx.x;
  const int lane = tid & 63;
  const int w = tid >> 6;
  const float NEG = -__builtin_inff();

  // ---- 1) compaction map ----
  int flag = 0, pre = 0;
  if (tid < NN) flag = dmask[d * NN + tid];
  if (tid < 192) {   // waves 0..2
    unsigned long long bal = __ballot(flag != 0);
    pre = __popcll(bal & ((1ull << lane) - 1ull));
    if (lane == 63) wtot[w] = pre + (flag ? 1 : 0);
  }
  __syncthreads();
  const int cnt = wtot[0] + wtot[1] + wtot[2];
  if (tid < 192 && flag) {
    int base = (w >= 1 ? wtot[0] : 0) + (w >= 2 ? wtot[1] : 0);
    mapinv[pre + base] = (unsigned short)tid;
  }
  __syncthreads();

  // ---- 2) stage compacted bf16 frag tiles (one 16B slot per thread-iter) ----
  const int ntc = (cnt + 15) >> 4;
  for (int s = tid; s < ntc * 256; s += 512) {
    int nt = s >> 8, ks = (s >> 6) & 3, ln = s & 63;
    int bl2 = ln & 15, bg2 = ln >> 4;
    int dr = nt * 16 + bl2;
    uint4 o = make_uint4(0u, 0u, 0u, 0u);
    if (dr < cnt) {
      int sr = mapinv[dr];
      const float4* p = reinterpret_cast<const float4*>(D) +
                        (size_t)(d * NN + sr) * 32 + ks * 8 + bg2 * 2;
      o = pack8(p[0], p[1]);
    }
    *reinterpret_cast<uint4*>(&Dlds[(size_t)s * 16]) = o;
  }
  __syncthreads();

  // ---- 3) compute: wave w owns queries w*4 .. w*4+3, two sequential pairs ----
  const int bg = lane >> 4;

  #pragma unroll 1
  for (int p = 0; p < 2; ++p) {
    const int q0 = w * 4 + p * 2;

    short8 Qf[2][2][4];  // [qi][mt][ks], 64 VGPR, coalesced 16B/lane from L2-hot Qb
    #pragma unroll
    for (int qi = 0; qi < 2; ++qi)
      #pragma unroll
      for (int mt = 0; mt < 2; ++mt)
        #pragma unroll
        for (int ks = 0; ks < 4; ++ks)
          Qf[qi][mt][ks] = *reinterpret_cast<const short8*>(
              reinterpret_cast<const char*>(Qb) +
              ((((q0 + qi) * 2 + mt) * 4 + ks) << 10) + (lane << 4));

    float run[2][2];
    #pragma unroll
    for (int qi = 0; qi < 2; ++qi)
      #pragma unroll
      for (int mt = 0; mt < 2; ++mt) run[qi][mt] = NEG;

    #pragma unroll 2
    for (int nt = 0; nt < ntc; ++nt) {
      short8 Da[4];
      #pragma unroll
      for (int ks = 0; ks < 4; ++ks)
        Da[ks] = *reinterpret_cast<const short8*>(
            &Dlds[((nt * 4 + ks) << 10) + (lane << 4)]);

      f32x4 acc[2][2];
      #pragma unroll
      for (int qi = 0; qi < 2; ++qi)
        #pragma unroll
        for (int mt = 0; mt < 2; ++mt) acc[qi][mt] = (f32x4){0.f, 0.f, 0.f, 0.f};

      #pragma unroll
      for (int ks = 0; ks < 4; ++ks)
        #pragma unroll
        for (int qi = 0; qi < 2; ++qi)
          #pragma unroll
          for (int mt = 0; mt < 2; ++mt)
            acc[qi][mt] = __builtin_amdgcn_mfma_f32_16x16x32_bf16(
                Da[ks], Qf[qi][mt][ks], acc[qi][mt], 0, 0, 0);

      if (nt * 16 + 16 > cnt) {
        // tail tile: lane holds rows nt*16 + bg*4 + j; valid iff j < rlim
        const int rlim = cnt - nt * 16 - bg * 4;
        #pragma unroll
        for (int qi = 0; qi < 2; ++qi)
          #pragma unroll
          for (int mt = 0; mt < 2; ++mt) {
            float vmax = NEG;
            #pragma unroll
            for (int j = 0; j < 4; ++j) {
              float v = (j < rlim) ? acc[qi][mt][j] : NEG;
              vmax = fmaxf(vmax, v);
            }
            run[qi][mt] = fmaxf(run[qi][mt], vmax);
          }
      } else {
        #pragma unroll
        for (int qi = 0; qi < 2; ++qi)
          #pragma unroll
          for (int mt = 0; mt < 2; ++mt) {
            float vmax = fmaxf(fmaxf(acc[qi][mt][0], acc[qi][mt][1]),
                               fmaxf(acc[qi][mt][2], acc[qi][mt][3]));
            run[qi][mt] = fmaxf(run[qi][mt], vmax);
          }
      }
    }

    // masked doc tokens inject an exact 0 into max_n
    if (cnt < NN) {
      #pragma unroll
      for (int qi = 0; qi < 2; ++qi)
        #pragma unroll
        for (int mt = 0; mt < 2; ++mt) run[qi][mt] = fmaxf(run[qi][mt], 0.f);
    }

    // reduction: xor16/32 max over n-quarters, xor1..8 sum over m
    #pragma unroll
    for (int qi = 0; qi < 2; ++qi) {
      float a = run[qi][0];   // m = lane&15
      float bb = run[qi][1];  // m = (lane&15)+16
      a = fmaxf(a, __shfl_xor(a, 16));
      a = fmaxf(a, __shfl_xor(a, 32));
      bb = fmaxf(bb, __shfl_xor(bb, 16));
      bb = fmaxf(bb, __shfl_xor(bb, 32));
      float s = a + bb;
      s += __shfl_xor(s, 1);
      s += __shfl_xor(s, 2);
      s += __shfl_xor(s, 4);
      s += __shfl_xor(s, 8);
      if (lane == 0) out[(q0 + qi) * ND + d] = s;
    }
  }
}

extern "C" void kernel_launch(void* const* d_in, const int* in_sizes, int n_in,
                              void* d_out, int out_size, void* d_ws, size_t ws_size,
                              hipStream_t stream) {
  const float* Q = (const float*)d_in[0];
  const float* D = (const float*)d_in[1];
  const int* qmask = (const int*)d_in[2];
  const int* dmask = (const int*)d_in[3];
  float* out = (float*)d_out;
  unsigned short* Qb = (unsigned short*)d_ws;   // 256 KB frag-ordered Q

  prep_q_frag<<<16384 / 256, 256, 0, stream>>>(Q, qmask, Qb);
  fused_maxsim<<<ND, 512, 0, stream>>>(D, dmask, Qb, out);
}

// Round 22
// 22.174 us; speedup vs baseline: 1.3283x; 1.1735x over previous
//
#include <hip/hip_runtime.h>
#include <hip/hip_bf16.h>

typedef __attribute__((ext_vector_type(8))) short short8;
typedef __attribute__((ext_vector_type(4))) float f32x4;

#define NQ 32      // queries
#define NM 32      // query tokens
#define NH 128     // head dim
#define ND 512     // docs
#define NN 180     // doc tokens
#define NTMAX 12   // max compacted doc n-tiles (192 rows)
#define MTILES 64  // max query m-tiles (1024 tokens / 16)

#define QFRAG_BYTES (MTILES * 4 * 64 * 16)    // 256 KB frag-ordered compacted Q
#define QSTART_OFF  QFRAG_BYTES               // int[33]
#define T2_OFF      (QSTART_OFF + 33 * 4)     // int

static __device__ __forceinline__ unsigned short f2bf(float x) {
  __hip_bfloat16 h = __float2bfloat16(x);
  return __builtin_bit_cast(unsigned short, h);
}

static __device__ __forceinline__ uint4 pack8(float4 a, float4 b) {
  unsigned int x = (unsigned)f2bf(a.x) | ((unsigned)f2bf(a.y) << 16);
  unsigned int y = (unsigned)f2bf(a.z) | ((unsigned)f2bf(a.w) << 16);
  unsigned int z = (unsigned)f2bf(b.x) | ((unsigned)f2bf(b.y) << 16);
  unsigned int u = (unsigned)f2bf(b.z) | ((unsigned)f2bf(b.w) << 16);
  return make_uint4(x, y, z, u);
}

// Fragment layout (16x16x32 bf16, swapped operands): element (lane,j) of tile
// (t, ks) = M[t*16 + (lane&15)][ks*32 + (lane>>4)*8 + j], stored 16B/lane.
//
// prep: GLOBAL QUERY-TOKEN COMPACTION. A masked query token's Qm row is 0 ->
// all sims 0 -> max_n = 0 -> contributes exactly 0 to sum_m. So only valid
// (q,m) tokens (sorted by q) are packed into m-tiles of 16 columns:
// T = ceil(total/16) ~ 33 tiles instead of 64 -> MFMA work ~halves.
// 64 blocks x 1024 thr; every block redundantly ballot-scans the 1024 flags
// (trivial), then threads 0..255 of block b write frag slots b*256+tid
// (2 float4 loads + pack; valid => qmask==1, no multiply; pad cols = 0).
// Block 0 also writes qstart[33] (per-query column ranges) and T2.
__global__ __launch_bounds__(1024) void prep_q_compact(
    const float* __restrict__ Q, const int* __restrict__ qmask,
    unsigned short* __restrict__ Qb, int* __restrict__ qstart_g,
    int* __restrict__ t2_g) {
  __shared__ unsigned short src_tok[NQ * NM];
  __shared__ int wtot16[16], base16[16], total_s;
  const int tid = threadIdx.x;
  const int lane = tid & 63;
  const int wv = tid >> 6;

  // ---- redundant global scan over all 1024 (q,m) tokens ----
  const int flag = qmask[tid];
  unsigned long long bal = __ballot(flag != 0);
  int pre = __popcll(bal & ((1ull << lane) - 1ull));
  if (lane == 63) wtot16[wv] = pre + (flag ? 1 : 0);
  __syncthreads();
  if (tid == 0) {
    int run = 0;
    #pragma unroll
    for (int i = 0; i < 16; ++i) { base16[i] = run; run += wtot16[i]; }
    total_s = run;
  }
  __syncthreads();
  const int pos = base16[wv] + pre;   // # valid tokens strictly before tid
  if (flag) src_tok[pos] = (unsigned short)tid;
  if (blockIdx.x == 0 && (tid & 31) == 0) qstart_g[tid >> 5] = pos;
  __syncthreads();
  const int total = total_s;
  if (blockIdx.x == 0 && tid == 0) {
    qstart_g[32] = total;
    int T = (total + 15) >> 4;
    t2_g[0] = (T + 1) >> 1;   // tile pairs
  }

  // ---- frag build: one 16B slot per thread (threads 0..255) ----
  if (tid < 256) {
    int s = blockIdx.x * 256 + tid;        // 16384 slots = 64 tiles
    int t2 = s >> 8, ks = (s >> 6) & 3, ln = s & 63;
    int col = t2 * 16 + (ln & 15);
    int kk = ks * 32 + (ln >> 4) * 8;
    uint4 o = make_uint4(0u, 0u, 0u, 0u);
    if (col < total) {
      int tok = src_tok[col];              // (q<<5)|m, qmask==1
      const float* src = Q + tok * NH + kk;
      float4 a = *reinterpret_cast<const float4*>(src);
      float4 b = *reinterpret_cast<const float4*>(src + 4);
      o = pack8(a, b);
    }
    reinterpret_cast<uint4*>(Qb)[s] = o;
  }
}

// FUSED per-doc kernel (R14 body + compacted m-tiles): 512 blocks x 512 thr.
//  1) doc compaction map (ballot prefix-scan) -- unchanged
//  2) stage compacted VALID doc rows -> LDS bf16 frag tiles -- unchanged
//  3) waves process m-tile PAIRS tp = w, w+8, ... < T2 (~17 pairs vs fixed 32
//     m-tile-pairs before): per pair, 2 MFMA chains x ntc D-tiles, j-fold +
//     tail mask + 0-clamp, xor16/32 -> column max -> colmax LDS (no atomics).
//  4) barrier; threads 0..31 sum their query's contiguous column range
//     [qstart[q], qstart[q+1]) -> out. Deterministic.
__global__ __launch_bounds__(512, 4) void fused_maxsim(
    const float* __restrict__ D, const int* __restrict__ dmask,
    const unsigned short* __restrict__ Qb, const int* __restrict__ qstart_g,
    const int* __restrict__ t2_g, float* __restrict__ out) {
  __shared__ unsigned char Dlds[NTMAX * 4096];   // 49152 B
  __shared__ float colmax[MTILES * 16];          // 4 KB
  __shared__ unsigned short mapinv[192];
  __shared__ int wtot[4];
  const int d = blockIdx.x;
  const int tid = threadIdx.x;
  const int lane = tid & 63;
  const int w = tid >> 6;
  const float NEG = -__builtin_inff();

  // ---- 1) doc compaction map ----
  int flag = 0, pre = 0;
  if (tid < NN) flag = dmask[d * NN + tid];
  if (tid < 192) {   // waves 0..2
    unsigned long long bal = __ballot(flag != 0);
    pre = __popcll(bal & ((1ull << lane) - 1ull));
    if (lane == 63) wtot[w] = pre + (flag ? 1 : 0);
  }
  __syncthreads();
  const int cnt = wtot[0] + wtot[1] + wtot[2];
  if (tid < 192 && flag) {
    int base = (w >= 1 ? wtot[0] : 0) + (w >= 2 ? wtot[1] : 0);
    mapinv[pre + base] = (unsigned short)tid;
  }
  __syncthreads();

  // ---- 2) stage compacted doc rows -> LDS bf16 frag tiles ----
  const int ntc = (cnt + 15) >> 4;
  for (int s = tid; s < ntc * 256; s += 512) {
    int nt = s >> 8, ks = (s >> 6) & 3, ln = s & 63;
    int bl2 = ln & 15, bg2 = ln >> 4;
    int dr = nt * 16 + bl2;
    uint4 o = make_uint4(0u, 0u, 0u, 0u);
    if (dr < cnt) {
      int sr = mapinv[dr];
      const float4* p = reinterpret_cast<const float4*>(D) +
                        (size_t)(d * NN + sr) * 32 + ks * 8 + bg2 * 2;
      o = pack8(p[0], p[1]);
    }
    *reinterpret_cast<uint4*>(&Dlds[(size_t)s * 16]) = o;
  }
  __syncthreads();

  // ---- 3) compute: m-tile pairs strided over waves ----
  const int bg = lane >> 4;
  const int T2 = t2_g[0];

  #pragma unroll 1
  for (int tp = w; tp < T2; tp += 8) {
    const int t0 = tp * 2;

    short8 Qf0[4], Qf1[4];   // 2 tiles x 4 ks = 32 VGPR, plain loads
    #pragma unroll
    for (int ks = 0; ks < 4; ++ks) {
      Qf0[ks] = *reinterpret_cast<const short8*>(
          reinterpret_cast<const char*>(Qb) +
          (((t0 * 4 + ks) << 10) + (lane << 4)));
      Qf1[ks] = *reinterpret_cast<const short8*>(
          reinterpret_cast<const char*>(Qb) +
          ((((t0 + 1) * 4 + ks) << 10) + (lane << 4)));
    }

    float run0 = NEG, run1 = NEG;

    #pragma unroll 2
    for (int nt = 0; nt < ntc; ++nt) {
      short8 Da[4];
      #pragma unroll
      for (int ks = 0; ks < 4; ++ks)
        Da[ks] = *reinterpret_cast<const short8*>(
            &Dlds[((nt * 4 + ks) << 10) + (lane << 4)]);

      f32x4 acc0 = {0.f, 0.f, 0.f, 0.f};
      f32x4 acc1 = acc0;
      #pragma unroll
      for (int ks = 0; ks < 4; ++ks) {
        acc0 = __builtin_amdgcn_mfma_f32_16x16x32_bf16(Da[ks], Qf0[ks], acc0, 0, 0, 0);
        acc1 = __builtin_amdgcn_mfma_f32_16x16x32_bf16(Da[ks], Qf1[ks], acc1, 0, 0, 0);
      }

      if (nt * 16 + 16 > cnt) {
        // tail tile: lane holds rows nt*16 + bg*4 + j; valid iff j < rlim
        const int rlim = cnt - nt * 16 - bg * 4;
        float v0 = NEG, v1 = NEG;
        #pragma unroll
        for (int j = 0; j < 4; ++j) {
          v0 = fmaxf(v0, (j < rlim) ? acc0[j] : NEG);
          v1 = fmaxf(v1, (j < rlim) ? acc1[j] : NEG);
        }
        run0 = fmaxf(run0, v0);
        run1 = fmaxf(run1, v1);
      } else {
        run0 = fmaxf(run0, fmaxf(fmaxf(acc0[0], acc0[1]), fmaxf(acc0[2], acc0[3])));
        run1 = fmaxf(run1, fmaxf(fmaxf(acc1[0], acc1[1]), fmaxf(acc1[2], acc1[3])));
      }
    }

    // masked doc tokens inject an exact 0 into max_n
    if (cnt < NN) {
      run0 = fmaxf(run0, 0.f);
      run1 = fmaxf(run1, 0.f);
    }

    // column max across the 4 n-quarters
    run0 = fmaxf(run0, __shfl_xor(run0, 16));
    run0 = fmaxf(run0, __shfl_xor(run0, 32));
    run1 = fmaxf(run1, __shfl_xor(run1, 16));
    run1 = fmaxf(run1, __shfl_xor(run1, 32));

    if (lane < 16) {
      colmax[t0 * 16 + lane] = run0;
      colmax[(t0 + 1) * 16 + lane] = run1;
    }
  }
  __syncthreads();

  // ---- 4) per-query sum over its contiguous column range ----
  if (tid < NQ) {
    const int s0 = qstart_g[tid];
    const int s1 = qstart_g[tid + 1];
    float s = 0.f;
    for (int i = s0; i < s1; ++i) s += colmax[i];
    out[tid * ND + d] = s;
  }
}

extern "C" void kernel_launch(void* const* d_in, const int* in_sizes, int n_in,
                              void* d_out, int out_size, void* d_ws, size_t ws_size,
                              hipStream_t stream) {
  const float* Q = (const float*)d_in[0];
  const float* D = (const float*)d_in[1];
  const int* qmask = (const int*)d_in[2];
  const int* dmask = (const int*)d_in[3];
  float* out = (float*)d_out;

  unsigned short* Qb = (unsigned short*)d_ws;
  int* qstart_g = (int*)((char*)d_ws + QSTART_OFF);
  int* t2_g = (int*)((char*)d_ws + T2_OFF);

  prep_q_compact<<<64, 1024, 0, stream>>>(Q, qmask, Qb, qstart_g, t2_g);
  fused_maxsim<<<ND, 512, 0, stream>>>(D, dmask, Qb, qstart_g, t2_g, out);
}

// Round 23
// 21.639 us; speedup vs baseline: 1.3611x; 1.0247x over previous
//
#include <hip/hip_runtime.h>
#include <hip/hip_bf16.h>

typedef __attribute__((ext_vector_type(8))) short short8;
typedef __attribute__((ext_vector_type(4))) float f32x4;

#define NQ 32      // queries
#define NM 32      // query tokens
#define NH 128     // head dim
#define ND 512     // docs
#define NN 180     // doc tokens
#define NTMAX 12   // max compacted doc n-tiles (192 rows)
#define MTILES 64  // max query m-tiles
#define LSTR 136   // LDS row stride in shorts (272 B; 2-way banks on b128 reads = free)

#define QFRAG_BYTES (MTILES * 4 * 64 * 16)    // 256 KB frag-ordered compacted Q
#define QSTART_OFF  QFRAG_BYTES               // int[33]
#define T2_OFF      (QSTART_OFF + 33 * 4)     // int

static __device__ __forceinline__ unsigned short f2bf(float x) {
  __hip_bfloat16 h = __float2bfloat16(x);
  return __builtin_bit_cast(unsigned short, h);
}

static __device__ __forceinline__ uint4 pack8(float4 a, float4 b) {
  unsigned int x = (unsigned)f2bf(a.x) | ((unsigned)f2bf(a.y) << 16);
  unsigned int y = (unsigned)f2bf(a.z) | ((unsigned)f2bf(a.w) << 16);
  unsigned int z = (unsigned)f2bf(b.x) | ((unsigned)f2bf(b.y) << 16);
  unsigned int u = (unsigned)f2bf(b.z) | ((unsigned)f2bf(b.w) << 16);
  return make_uint4(x, y, z, u);
}

// prep: GLOBAL QUERY-TOKEN COMPACTION (R22-proven). Valid (q,m) tokens sorted
// by q, packed into 16-column m-tiles; T ~ 33 tiles instead of 64. Qb is
// MFMA-frag-ordered: element (lane,j) of tile (t,ks) = Qc[t*16+(lane&15)]
// [ks*32+(lane>>4)*8+j], stored 16B/lane.
__global__ __launch_bounds__(1024) void prep_q_compact(
    const float* __restrict__ Q, const int* __restrict__ qmask,
    unsigned short* __restrict__ Qb, int* __restrict__ qstart_g,
    int* __restrict__ t2_g) {
  __shared__ unsigned short src_tok[NQ * NM];
  __shared__ int wtot16[16], base16[16], total_s;
  const int tid = threadIdx.x;
  const int lane = tid & 63;
  const int wv = tid >> 6;

  const int flag = qmask[tid];
  unsigned long long bal = __ballot(flag != 0);
  int pre = __popcll(bal & ((1ull << lane) - 1ull));
  if (lane == 63) wtot16[wv] = pre + (flag ? 1 : 0);
  __syncthreads();
  if (tid == 0) {
    int run = 0;
    #pragma unroll
    for (int i = 0; i < 16; ++i) { base16[i] = run; run += wtot16[i]; }
    total_s = run;
  }
  __syncthreads();
  const int pos = base16[wv] + pre;
  if (flag) src_tok[pos] = (unsigned short)tid;
  if (blockIdx.x == 0 && (tid & 31) == 0) qstart_g[tid >> 5] = pos;
  __syncthreads();
  const int total = total_s;
  if (blockIdx.x == 0 && tid == 0) {
    qstart_g[32] = total;
    int T = (total + 15) >> 4;
    t2_g[0] = (T + 1) >> 1;
  }

  if (tid < 256) {
    int s = blockIdx.x * 256 + tid;        // 16384 slots = 64 tiles
    int t2 = s >> 8, ks = (s >> 6) & 3, ln = s & 63;
    int col = t2 * 16 + (ln & 15);
    int kk = ks * 32 + (ln >> 4) * 8;
    uint4 o = make_uint4(0u, 0u, 0u, 0u);
    if (col < total) {
      int tok = src_tok[col];              // qmask==1 -> no multiply
      const float* src = Q + tok * NH + kk;
      float4 a = *reinterpret_cast<const float4*>(src);
      float4 b = *reinterpret_cast<const float4*>(src + 4);
      o = pack8(a, b);
    }
    reinterpret_cast<uint4*>(Qb)[s] = o;
  }
}

// FUSED per-doc kernel: 512 blocks x 512 thr (8 waves), 2 blocks/CU.
//  1) doc compaction map (ballot prefix-scan) — R14-proven
//  2) COALESCED ROW-GRANULAR STAGE (new): 32 threads per doc row, lane reads
//     one float4 contiguous in the row (512B-granular gather; mapinv lookup is
//     a free 32-lane broadcast), packs 4 floats -> 8B bf16, writes row-major
//     LDS at dr*LSTR + c4*4 shorts (consecutive lanes -> consecutive 8B ->
//     conflict-free). Replaces R22's 32B-scattered frag gather (~3072
//     transactions/block -> ~8 per row).
//  3) compute reads A-frags from row-major LDS (R1-R6-proven addressing,
//     2-way banks = free); m-tile PAIRS strided over waves (R22-proven).
//  4) colmax LDS + per-query contiguous-range sum (R22-proven).
__global__ __launch_bounds__(512, 4) void fused_maxsim(
    const float* __restrict__ D, const int* __restrict__ dmask,
    const unsigned short* __restrict__ Qb, const int* __restrict__ qstart_g,
    const int* __restrict__ t2_g, float* __restrict__ out) {
  __shared__ unsigned short Dlds[192 * LSTR];    // 52224 B row-major bf16
  __shared__ float colmax[MTILES * 16];          // 4 KB
  __shared__ unsigned short mapinv[192];
  __shared__ int wtot[4];
  const int d = blockIdx.x;
  const int tid = threadIdx.x;
  const int lane = tid & 63;
  const int w = tid >> 6;
  const float NEG = -__builtin_inff();

  // ---- 1) doc compaction map ----
  int flag = 0, pre = 0;
  if (tid < NN) flag = dmask[d * NN + tid];
  if (tid < 192) {   // waves 0..2
    unsigned long long bal = __ballot(flag != 0);
    pre = __popcll(bal & ((1ull << lane) - 1ull));
    if (lane == 63) wtot[w] = pre + (flag ? 1 : 0);
  }
  __syncthreads();
  const int cnt = wtot[0] + wtot[1] + wtot[2];
  if (tid < 192 && flag) {
    int base = (w >= 1 ? wtot[0] : 0) + (w >= 2 ? wtot[1] : 0);
    mapinv[pre + base] = (unsigned short)tid;
  }
  __syncthreads();

  // ---- 2) coalesced row-granular stage ----
  const int ntc = (cnt + 15) >> 4;
  {
    const int rg = tid >> 5;    // row-in-pass (0..15)
    const int c4 = tid & 31;    // float4 col within row
    const int nrows = ntc * 16;
    #pragma unroll 2
    for (int base = 0; base < nrows; base += 16) {
      int dr = base + rg;
      uint2 o = make_uint2(0u, 0u);
      if (dr < cnt) {
        int sr = mapinv[dr];    // same addr across the 32-lane group: broadcast
        float4 v = reinterpret_cast<const float4*>(D)[(size_t)(d * NN + sr) * 32 + c4];
        o.x = (unsigned)f2bf(v.x) | ((unsigned)f2bf(v.y) << 16);
        o.y = (unsigned)f2bf(v.z) | ((unsigned)f2bf(v.w) << 16);
      }
      *reinterpret_cast<uint2*>(&Dlds[dr * LSTR + c4 * 4]) = o;
    }
  }
  __syncthreads();

  // ---- 3) compute: m-tile pairs strided over waves ----
  const int bl = lane & 15;
  const int bg = lane >> 4;
  const int T2 = t2_g[0];

  #pragma unroll 1
  for (int tp = w; tp < T2; tp += 8) {
    const int t0 = tp * 2;

    short8 Qf0[4], Qf1[4];   // 2 m-tiles x 4 ks = 32 VGPR, plain loads
    #pragma unroll
    for (int ks = 0; ks < 4; ++ks) {
      Qf0[ks] = *reinterpret_cast<const short8*>(
          reinterpret_cast<const char*>(Qb) +
          (((t0 * 4 + ks) << 10) + (lane << 4)));
      Qf1[ks] = *reinterpret_cast<const short8*>(
          reinterpret_cast<const char*>(Qb) +
          ((((t0 + 1) * 4 + ks) << 10) + (lane << 4)));
    }

    float run0 = NEG, run1 = NEG;

    #pragma unroll 2
    for (int nt = 0; nt < ntc; ++nt) {
      short8 Da[4];
      #pragma unroll
      for (int ks = 0; ks < 4; ++ks)
        Da[ks] = *reinterpret_cast<const short8*>(
            &Dlds[(nt * 16 + bl) * LSTR + ks * 32 + bg * 8]);

      f32x4 acc0 = {0.f, 0.f, 0.f, 0.f};
      f32x4 acc1 = acc0;
      #pragma unroll
      for (int ks = 0; ks < 4; ++ks) {
        acc0 = __builtin_amdgcn_mfma_f32_16x16x32_bf16(Da[ks], Qf0[ks], acc0, 0, 0, 0);
        acc1 = __builtin_amdgcn_mfma_f32_16x16x32_bf16(Da[ks], Qf1[ks], acc1, 0, 0, 0);
      }

      if (nt * 16 + 16 > cnt) {
        // tail tile: lane holds rows nt*16 + bg*4 + j; valid iff j < rlim
        const int rlim = cnt - nt * 16 - bg * 4;
        float v0 = NEG, v1 = NEG;
        #pragma unroll
        for (int j = 0; j < 4; ++j) {
          v0 = fmaxf(v0, (j < rlim) ? acc0[j] : NEG);
          v1 = fmaxf(v1, (j < rlim) ? acc1[j] : NEG);
        }
        run0 = fmaxf(run0, v0);
        run1 = fmaxf(run1, v1);
      } else {
        run0 = fmaxf(run0, fmaxf(fmaxf(acc0[0], acc0[1]), fmaxf(acc0[2], acc0[3])));
        run1 = fmaxf(run1, fmaxf(fmaxf(acc1[0], acc1[1]), fmaxf(acc1[2], acc1[3])));
      }
    }

    // masked doc tokens inject an exact 0 into max_n
    if (cnt < NN) {
      run0 = fmaxf(run0, 0.f);
      run1 = fmaxf(run1, 0.f);
    }

    // column max across the 4 n-quarters
    run0 = fmaxf(run0, __shfl_xor(run0, 16));
    run0 = fmaxf(run0, __shfl_xor(run0, 32));
    run1 = fmaxf(run1, __shfl_xor(run1, 16));
    run1 = fmaxf(run1, __shfl_xor(run1, 32));

    if (lane < 16) {
      colmax[t0 * 16 + lane] = run0;
      colmax[(t0 + 1) * 16 + lane] = run1;
    }
  }
  __syncthreads();

  // ---- 4) per-query sum over its contiguous column range ----
  if (tid < NQ) {
    const int s0 = qstart_g[tid];
    const int s1 = qstart_g[tid + 1];
    float s = 0.f;
    for (int i = s0; i < s1; ++i) s += colmax[i];
    out[tid * ND + d] = s;
  }
}

extern "C" void kernel_launch(void* const* d_in, const int* in_sizes, int n_in,
                              void* d_out, int out_size, void* d_ws, size_t ws_size,
                              hipStream_t stream) {
  const float* Q = (const float*)d_in[0];
  const float* D = (const float*)d_in[1];
  const int* qmask = (const int*)d_in[2];
  const int* dmask = (const int*)d_in[3];
  float* out = (float*)d_out;

  unsigned short* Qb = (unsigned short*)d_ws;
  int* qstart_g = (int*)((char*)d_ws + QSTART_OFF);
  int* t2_g = (int*)((char*)d_ws + T2_OFF);

  prep_q_compact<<<64, 1024, 0, stream>>>(Q, qmask, Qb, qstart_g, t2_g);
  fused_maxsim<<<ND, 512, 0, stream>>>(D, dmask, Qb, qstart_g, t2_g, out);
}

// Round 24
// 21.613 us; speedup vs baseline: 1.3627x; 1.0012x over previous
//
#include <hip/hip_runtime.h>
#include <hip/hip_bf16.h>

typedef __attribute__((ext_vector_type(8))) short short8;
typedef __attribute__((ext_vector_type(4))) float f32x4;

#define NQ 32      // queries
#define NM 32      // query tokens
#define NH 128     // head dim
#define ND 512     // docs
#define NN 180     // doc tokens
#define NTMAX 12   // max compacted doc n-tiles (192 rows)
#define MTILES 64  // max query m-tiles
#define LSTR 136   // LDS row stride in shorts (272 B; 2-way banks = free)

#define QFRAG_BYTES (MTILES * 4 * 64 * 16)    // 256 KB frag-ordered compacted Q
#define QSTART_OFF  QFRAG_BYTES               // int[33]
#define T2_OFF      (QSTART_OFF + 33 * 4)     // int

static __device__ __forceinline__ unsigned short f2bf(float x) {
  __hip_bfloat16 h = __float2bfloat16(x);
  return __builtin_bit_cast(unsigned short, h);
}

static __device__ __forceinline__ uint4 pack8(float4 a, float4 b) {
  unsigned int x = (unsigned)f2bf(a.x) | ((unsigned)f2bf(a.y) << 16);
  unsigned int y = (unsigned)f2bf(a.z) | ((unsigned)f2bf(a.w) << 16);
  unsigned int z = (unsigned)f2bf(b.x) | ((unsigned)f2bf(b.y) << 16);
  unsigned int u = (unsigned)f2bf(b.z) | ((unsigned)f2bf(b.w) << 16);
  return make_uint4(x, y, z, u);
}

// prep: GLOBAL QUERY-TOKEN COMPACTION (R22-proven outputs), now 64x256:
// each block scans the 1024 qmask flags in 4 ballot rounds (all threads),
// then builds 256 frag slots (threads fully used; old 1024-thr version
// idled 75% in frag-build). Block 0 writes qstart[33] + T2.
__global__ __launch_bounds__(256) void prep_q_compact(
    const float* __restrict__ Q, const int* __restrict__ qmask,
    unsigned short* __restrict__ Qb, int* __restrict__ qstart_g,
    int* __restrict__ t2_g) {
  __shared__ unsigned short src_tok[NQ * NM];
  __shared__ int rtot[16];   // per (round, wave) counts: [r*4 + wv]
  const int tid = threadIdx.x;
  const int lane = tid & 63;
  const int wv = tid >> 6;

  // ---- scan 1024 flags: 4 rounds x 256 threads ----
  int flags[4], pres[4];
  #pragma unroll
  for (int r = 0; r < 4; ++r) {
    int idx = r * 256 + tid;
    int f = qmask[idx];
    unsigned long long bal = __ballot(f != 0);
    int pre = __popcll(bal & ((1ull << lane) - 1ull));
    if (lane == 63) rtot[r * 4 + wv] = pre + (f ? 1 : 0);
    flags[r] = f;
    pres[r] = pre;
  }
  __syncthreads();
  // exclusive prefix over the 16 (round,wave) chunks — tiny, all threads
  int total = 0;
  int chunkbase[4];
  {
    int run = 0;
    #pragma unroll
    for (int r = 0; r < 4; ++r) {
      chunkbase[r] = run + ((wv >= 1) ? rtot[r * 4 + 0] : 0) +
                           ((wv >= 2) ? rtot[r * 4 + 1] : 0) +
                           ((wv >= 3) ? rtot[r * 4 + 2] : 0);
      run += rtot[r * 4 + 0] + rtot[r * 4 + 1] + rtot[r * 4 + 2] + rtot[r * 4 + 3];
    }
    total = run;
  }
  #pragma unroll
  for (int r = 0; r < 4; ++r) {
    int idx = r * 256 + tid;
    int pos = chunkbase[r] + pres[r];
    if (flags[r]) src_tok[pos] = (unsigned short)idx;
    if (blockIdx.x == 0 && (idx & 31) == 0) qstart_g[idx >> 5] = pos;
  }
  __syncthreads();
  if (blockIdx.x == 0 && tid == 0) {
    qstart_g[32] = total;
    int T = (total + 15) >> 4;
    t2_g[0] = (T + 1) >> 1;
  }

  // ---- frag build: one 16B slot per thread ----
  {
    int s = blockIdx.x * 256 + tid;        // 16384 slots = 64 tiles
    int t2 = s >> 8, ks = (s >> 6) & 3, ln = s & 63;
    int col = t2 * 16 + (ln & 15);
    int kk = ks * 32 + (ln >> 4) * 8;
    uint4 o = make_uint4(0u, 0u, 0u, 0u);
    if (col < total) {
      int tok = src_tok[col];              // qmask==1 -> no multiply
      const float* src = Q + tok * NH + kk;
      float4 a = *reinterpret_cast<const float4*>(src);
      float4 b = *reinterpret_cast<const float4*>(src + 4);
      o = pack8(a, b);
    }
    reinterpret_cast<uint4*>(Qb)[s] = o;
  }
}

// FUSED per-doc kernel (R23 body + first-pair Qf prefetch + deeper stage
// unroll): 512 blocks x 512 thr (8 waves), 2 blocks/CU, 4 waves/SIMD.
__global__ __launch_bounds__(512, 4) void fused_maxsim(
    const float* __restrict__ D, const int* __restrict__ dmask,
    const unsigned short* __restrict__ Qb, const int* __restrict__ qstart_g,
    const int* __restrict__ t2_g, float* __restrict__ out) {
  __shared__ unsigned short Dlds[192 * LSTR];    // 52224 B row-major bf16
  __shared__ float colmax[MTILES * 16];          // 4 KB
  __shared__ unsigned short mapinv[192];
  __shared__ int wtot[4];
  const int d = blockIdx.x;
  const int tid = threadIdx.x;
  const int lane = tid & 63;
  const int w = tid >> 6;
  const float NEG = -__builtin_inff();

  // ---- 1) doc compaction map ----
  int flag = 0, pre = 0;
  if (tid < NN) flag = dmask[d * NN + tid];
  if (tid < 192) {   // waves 0..2
    unsigned long long bal = __ballot(flag != 0);
    pre = __popcll(bal & ((1ull << lane) - 1ull));
    if (lane == 63) wtot[w] = pre + (flag ? 1 : 0);
  }
  __syncthreads();
  const int cnt = wtot[0] + wtot[1] + wtot[2];
  if (tid < 192 && flag) {
    int base = (w >= 1 ? wtot[0] : 0) + (w >= 2 ? wtot[1] : 0);
    mapinv[pre + base] = (unsigned short)tid;
  }
  __syncthreads();

  const int T2 = t2_g[0];

  // ---- Qf prefetch for this wave's FIRST m-tile pair (hides L2 latency
  //      under the stage phase; loads are issued before any LDS dependency) ----
  short8 Qp0[4], Qp1[4];
  const bool hasFirst = (w < T2);
  {
    const int t0 = w * 2;
    #pragma unroll
    for (int ks = 0; ks < 4; ++ks) {
      Qp0[ks] = *reinterpret_cast<const short8*>(
          reinterpret_cast<const char*>(Qb) +
          (((t0 * 4 + ks) << 10) + (lane << 4)));
      Qp1[ks] = *reinterpret_cast<const short8*>(
          reinterpret_cast<const char*>(Qb) +
          ((((t0 + 1) * 4 + ks) << 10) + (lane << 4)));
    }
  }

  // ---- 2) coalesced row-granular stage (unroll 4: more loads in flight) ----
  const int ntc = (cnt + 15) >> 4;
  {
    const int rg = tid >> 5;    // row-in-pass (0..15)
    const int c4 = tid & 31;    // float4 col within row
    const int nrows = ntc * 16;
    #pragma unroll 4
    for (int base = 0; base < nrows; base += 16) {
      int dr = base + rg;
      uint2 o = make_uint2(0u, 0u);
      if (dr < cnt) {
        int sr = mapinv[dr];    // broadcast across the 32-lane group
        float4 v = reinterpret_cast<const float4*>(D)[(size_t)(d * NN + sr) * 32 + c4];
        o.x = (unsigned)f2bf(v.x) | ((unsigned)f2bf(v.y) << 16);
        o.y = (unsigned)f2bf(v.z) | ((unsigned)f2bf(v.w) << 16);
      }
      *reinterpret_cast<uint2*>(&Dlds[dr * LSTR + c4 * 4]) = o;
    }
  }
  __syncthreads();

  // ---- 3) compute: m-tile pairs strided over waves ----
  const int bl = lane & 15;
  const int bg = lane >> 4;

  #pragma unroll 1
  for (int tp = w; tp < T2; tp += 8) {
    const int t0 = tp * 2;

    short8 Qf0[4], Qf1[4];
    if (tp == w) {
      #pragma unroll
      for (int ks = 0; ks < 4; ++ks) { Qf0[ks] = Qp0[ks]; Qf1[ks] = Qp1[ks]; }
    } else {
      #pragma unroll
      for (int ks = 0; ks < 4; ++ks) {
        Qf0[ks] = *reinterpret_cast<const short8*>(
            reinterpret_cast<const char*>(Qb) +
            (((t0 * 4 + ks) << 10) + (lane << 4)));
        Qf1[ks] = *reinterpret_cast<const short8*>(
            reinterpret_cast<const char*>(Qb) +
            ((((t0 + 1) * 4 + ks) << 10) + (lane << 4)));
      }
    }

    float run0 = NEG, run1 = NEG;

    #pragma unroll 2
    for (int nt = 0; nt < ntc; ++nt) {
      short8 Da[4];
      #pragma unroll
      for (int ks = 0; ks < 4; ++ks)
        Da[ks] = *reinterpret_cast<const short8*>(
            &Dlds[(nt * 16 + bl) * LSTR + ks * 32 + bg * 8]);

      f32x4 acc0 = {0.f, 0.f, 0.f, 0.f};
      f32x4 acc1 = acc0;
      #pragma unroll
      for (int ks = 0; ks < 4; ++ks) {
        acc0 = __builtin_amdgcn_mfma_f32_16x16x32_bf16(Da[ks], Qf0[ks], acc0, 0, 0, 0);
        acc1 = __builtin_amdgcn_mfma_f32_16x16x32_bf16(Da[ks], Qf1[ks], acc1, 0, 0, 0);
      }

      if (nt * 16 + 16 > cnt) {
        const int rlim = cnt - nt * 16 - bg * 4;   // lane rows: nt*16+bg*4+j
        float v0 = NEG, v1 = NEG;
        #pragma unroll
        for (int j = 0; j < 4; ++j) {
          v0 = fmaxf(v0, (j < rlim) ? acc0[j] : NEG);
          v1 = fmaxf(v1, (j < rlim) ? acc1[j] : NEG);
        }
        run0 = fmaxf(run0, v0);
        run1 = fmaxf(run1, v1);
      } else {
        run0 = fmaxf(run0, fmaxf(fmaxf(acc0[0], acc0[1]), fmaxf(acc0[2], acc0[3])));
        run1 = fmaxf(run1, fmaxf(fmaxf(acc1[0], acc1[1]), fmaxf(acc1[2], acc1[3])));
      }
    }

    // masked doc tokens inject an exact 0 into max_n
    if (cnt < NN) {
      run0 = fmaxf(run0, 0.f);
      run1 = fmaxf(run1, 0.f);
    }

    // column max across the 4 n-quarters
    run0 = fmaxf(run0, __shfl_xor(run0, 16));
    run0 = fmaxf(run0, __shfl_xor(run0, 32));
    run1 = fmaxf(run1, __shfl_xor(run1, 16));
    run1 = fmaxf(run1, __shfl_xor(run1, 32));

    if (lane < 16) {
      colmax[t0 * 16 + lane] = run0;
      colmax[(t0 + 1) * 16 + lane] = run1;
    }
  }
  __syncthreads();

  // ---- 4) per-query sum over its contiguous column range ----
  if (tid < NQ) {
    const int s0 = qstart_g[tid];
    const int s1 = qstart_g[tid + 1];
    float s = 0.f;
    for (int i = s0; i < s1; ++i) s += colmax[i];
    out[tid * ND + d] = s;
  }
}

extern "C" void kernel_launch(void* const* d_in, const int* in_sizes, int n_in,
                              void* d_out, int out_size, void* d_ws, size_t ws_size,
                              hipStream_t stream) {
  const float* Q = (const float*)d_in[0];
  const float* D = (const float*)d_in[1];
  const int* qmask = (const int*)d_in[2];
  const int* dmask = (const int*)d_in[3];
  float* out = (float*)d_out;

  unsigned short* Qb = (unsigned short*)d_ws;
  int* qstart_g = (int*)((char*)d_ws + QSTART_OFF);
  int* t2_g = (int*)((char*)d_ws + T2_OFF);

  prep_q_compact<<<64, 256, 0, stream>>>(Q, qmask, Qb, qstart_g, t2_g);
  fused_maxsim<<<ND, 512, 0, stream>>>(D, dmask, Qb, qstart_g, t2_g, out);
}